// Round 5
// baseline (355.993 us; speedup 1.0000x reference)
//
#include <hip/hip_runtime.h>

// DIAGNOSTIC ROUND: R1 gather kernel with internal 3x repeat so our dispatch
// (~370 us) outranks the harness's ~240 us fillBufferAligned dispatches in the
// top-5 counter table. All 3 reps write identical correct data (idempotent);
// asm memory clobber between reps prevents the compiler from eliding reps.
//
// Decision rule:
//   FETCH_SIZE ~ 1.0 GB (3x330 MB) -> gathers miss L3, HBM-fetch-bound ->
//       next: bucketed/compacted gather restructuring.
//   FETCH_SIZE < 0.3 GB            -> gathers L3-hit, NOT BW-bound ->
//       next: latency/MLP fixes (L2-resident slices, deeper unroll).
//
// out[m, k*64 + f] = nidx[m,k] < 0 ? 0 : features[nidx[m,k], f]
// features: [100000, 64] f32 (25.6 MB), nidx: [50000,32] i32, out: [50000,2048] f32.

typedef float f32x4 __attribute__((ext_vector_type(4)));

constexpr int K_NEIGH = 32;
constexpr int F4 = 16;        // 64 floats = 16 float4 per feature row
constexpr int REPS = 3;       // diagnostic repeat factor

__global__ void gcr_diag_kernel(const f32x4* __restrict__ feat4,
                                const int* __restrict__ nidx,
                                f32x4* __restrict__ out4,
                                long long total4) {
    const long long t0 = (long long)blockIdx.x * blockDim.x + threadIdx.x;
    const long long stride = (long long)gridDim.x * blockDim.x;
    for (int r = 0; r < REPS; ++r) {
        for (long long t = t0; t < total4; t += stride) {
            const int m = (int)(t >> 9);       // 512 float4 per output row
            const int q = (int)(t & 511);
            const int k = q >> 4;              // neighbor slot
            const int e = q & 15;              // float4 index within feature row
            const int idx = nidx[m * K_NEIGH + k];
            f32x4 v;
            if (idx < 0) {
                v = (f32x4)(0.f);
            } else {
                v = feat4[(long long)idx * F4 + e];
            }
            out4[t] = v;                       // plain store, identical to R1
        }
        asm volatile("" ::: "memory");         // block rep elision (rule #17)
    }
}

extern "C" void kernel_launch(void* const* d_in, const int* in_sizes, int n_in,
                              void* d_out, int out_size, void* d_ws, size_t ws_size,
                              hipStream_t stream) {
    const f32x4* feat4 = (const f32x4*)d_in[0];   // features [100000, 64] f32
    const int*   nidx  = (const int*)d_in[1];     // nidx [50000, 32] i32
    f32x4*       out4  = (f32x4*)d_out;           // [50000, 2048] f32

    const long long total4 = (long long)out_size / 4;   // 25.6M float4

    const int block = 256;
    long long want = (total4 + block - 1) / block;
    int grid = (int)(want < 2048 ? want : 2048);

    gcr_diag_kernel<<<grid, block, 0, stream>>>(feat4, nidx, out4, total4);
}

// Round 6
// 298.793 us; speedup vs baseline: 1.1914x; 1.1914x over previous
//
#include <hip/hip_runtime.h>

// DIAGNOSTIC A/B vs R5: identical 3x-rep gather kernel, ONLY change = stores
// are non-temporal (nidx load stays PLAIN — R3 confounded nt-load on nidx,
// which defeats cross-wave nidx line reuse).
//
// Question: does `nt` on the 400 MB/rep output stream prevent write-allocate
// in the memory-side Infinity Cache, keeping the 25.6 MB features resident?
//   Outcome A: FETCH 466 -> <100 MB, dur 356 -> <280 us  => ship R1+nt next.
//   Outcome B: FETCH ~ 440-470 MB, dur ~ 355-390 us      => excess fetch is
//              structural (MALL ignores nt); R1 is at the roofline.
//
// out[m, k*64 + f] = nidx[m,k] < 0 ? 0 : features[nidx[m,k], f]
// features: [100000, 64] f32 (25.6 MB), nidx: [50000,32] i32, out: [50000,2048] f32.

typedef float f32x4 __attribute__((ext_vector_type(4)));

constexpr int K_NEIGH = 32;
constexpr int F4 = 16;        // 64 floats = 16 float4 per feature row
constexpr int REPS = 3;       // diagnostic repeat factor (all reps idempotent)

__global__ void gcr_diag_nt_kernel(const f32x4* __restrict__ feat4,
                                   const int* __restrict__ nidx,
                                   f32x4* __restrict__ out4,
                                   long long total4) {
    const long long t0 = (long long)blockIdx.x * blockDim.x + threadIdx.x;
    const long long stride = (long long)gridDim.x * blockDim.x;
    for (int r = 0; r < REPS; ++r) {
        for (long long t = t0; t < total4; t += stride) {
            const int m = (int)(t >> 9);       // 512 float4 per output row
            const int q = (int)(t & 511);
            const int k = q >> 4;              // neighbor slot
            const int e = q & 15;              // float4 index within feature row
            const int idx = nidx[m * K_NEIGH + k];   // PLAIN load (reused across waves)
            f32x4 v;
            if (idx < 0) {
                v = (f32x4)(0.f);
            } else {
                v = feat4[(long long)idx * F4 + e];  // PLAIN load (12.8x reuse)
            }
            __builtin_nontemporal_store(v, &out4[t]); // nt: write-once stream
        }
        asm volatile("" ::: "memory");         // block rep elision (rule #17)
    }
}

extern "C" void kernel_launch(void* const* d_in, const int* in_sizes, int n_in,
                              void* d_out, int out_size, void* d_ws, size_t ws_size,
                              hipStream_t stream) {
    const f32x4* feat4 = (const f32x4*)d_in[0];   // features [100000, 64] f32
    const int*   nidx  = (const int*)d_in[1];     // nidx [50000, 32] i32
    f32x4*       out4  = (f32x4*)d_out;           // [50000, 2048] f32

    const long long total4 = (long long)out_size / 4;   // 25.6M float4

    const int block = 256;
    long long want = (total4 + block - 1) / block;
    int grid = (int)(want < 2048 ? want : 2048);

    gcr_diag_nt_kernel<<<grid, block, 0, stream>>>(feat4, nidx, out4, total4);
}

// Round 7
// 103.586 us; speedup vs baseline: 3.4367x; 2.8845x over previous
//
#include <hip/hip_runtime.h>

// GraphClusterReshape: out[m, k*64 + f] = nidx[m,k] < 0 ? 0 : features[nidx[m,k], f]
// features: [100000, 64] f32 (25.6 MB), nidx: [50000, 32] i32, out: [50000, 2048] f32 (409.6 MB).
//
// Final structure from R5/R6 diagnostics (3x-rep counter A/B):
//  - WRITE = 400 MB compulsory; FETCH = 144 MB/rep (32 MB compulsory + ~112 MB
//    gather re-fetch that survives all cache-hint attempts: MALL evicts the
//    25.6 MB feature set under the 400 MB write stream).
//  - nt on the output stream: −16% duration (write path skips write-allocate;
//    fetch barely moves). Loads stay PLAIN: nidx lines are reused by
//    consecutive 16-lane groups, features have 12.8x logical reuse (~60%
//    L3-hit even under thrash).
//  - Blocked multi-pass (R4) regressed: scan overhead ~+28 us > ~18 us
//    achievable fetch savings.
//
// Layout: one thread per output float4. 16 lanes = one neighbor row (64 f32);
// wave stores 1 KB contiguous; feature reads 256 B contiguous per group.

typedef float f32x4 __attribute__((ext_vector_type(4)));

constexpr int K_NEIGH = 32;
constexpr int F4 = 16;        // 64 floats = 16 float4 per feature row

__global__ void gcr_gather_nt_kernel(const f32x4* __restrict__ feat4,
                                     const int* __restrict__ nidx,
                                     f32x4* __restrict__ out4,
                                     long long total4) {
    long long t = (long long)blockIdx.x * blockDim.x + threadIdx.x;
    const long long stride = (long long)gridDim.x * blockDim.x;
    for (; t < total4; t += stride) {
        const int m = (int)(t >> 9);       // 512 float4 per output row
        const int q = (int)(t & 511);
        const int k = q >> 4;              // neighbor slot
        const int e = q & 15;              // float4 index within feature row
        const int idx = nidx[m * K_NEIGH + k];   // plain: cross-wave line reuse
        f32x4 v;
        if (idx < 0) {
            v = (f32x4)(0.f);
        } else {
            v = feat4[(long long)idx * F4 + e];  // plain: 12.8x logical reuse
        }
        __builtin_nontemporal_store(v, &out4[t]); // nt: write-once stream
    }
}

extern "C" void kernel_launch(void* const* d_in, const int* in_sizes, int n_in,
                              void* d_out, int out_size, void* d_ws, size_t ws_size,
                              hipStream_t stream) {
    const f32x4* feat4 = (const f32x4*)d_in[0];   // features [100000, 64] f32
    const int*   nidx  = (const int*)d_in[1];     // nidx [50000, 32] i32
    f32x4*       out4  = (f32x4*)d_out;           // [50000, 2048] f32

    const long long total4 = (long long)out_size / 4;   // 25.6M float4

    const int block = 256;
    long long want = (total4 + block - 1) / block;
    int grid = (int)(want < 2048 ? want : 2048);  // grid-stride, ~8 blocks/CU

    gcr_gather_nt_kernel<<<grid, block, 0, stream>>>(feat4, nidx, out4, total4);
}